// Round 8
// baseline (561.003 us; speedup 1.0000x reference)
//
#include <hip/hip_runtime.h>

// Problem constants (from reference setup_inputs): B=4, T=512, U=128, D=512, V=512
#define B_ 4
#define T_ 512
#define U_ 128
#define D_ 512
#define V_ 512
#define MS (B_ * T_)          // 2048 speech rows
#define MT (B_ * U_)          // 512 text rows
#define MTOT (MS + MT)        // 2560
#define LOGITS_ELEMS ((size_t)B_ * T_ * U_ * V_)   // 134217728

// GEMM tiling: 128x64 output tile, 256 threads, 8x4 per thread, K-tile 32,
// K-split x2 via blockIdx.z -> grid 20x8x2 = 320 blocks (proven 561us config,
// byte-identical to R3/R7).  LDS holds TRANSPOSED tiles (k-major): a-reads
// broadcast (conflict-free), b-reads 64 consecutive floats (2-way = free).
#define TM 128
#define TN 64
#define TK 32
#define XSTR 132              // Xt row stride (floats): 128 + 4, keeps 16B align
#define WSTR 68               // Wt row stride (floats): 64 + 4

// Partial-region layout (floats): [S (MS*V) | Tx (MT*V)] repeated per z.
#define S_ELEMS ((size_t)MS * V_)          // 1048576
#define TX_ELEMS ((size_t)MT * V_)         // 262144
#define PSTRIDE (S_ELEMS + TX_ELEMS)       // 1310720 floats per partial region
#define PS4 (PSTRIDE / 4)

#define V4_ (V_ / 4)          // 128

// bcast: u-quartered, LDS-staged. UQ quarters of UCHK=32 u-rows each.
#define UQ 4
#define UCHK (U_ / UQ)        // 32

typedef float f32x4 __attribute__((ext_vector_type(4)));

// Kernel 1: partial C = X * W[:, kbase:kbase+ktiles*TK]^T slice,
// X = concat(speech [2048,512], text [512,512]).
// Speech rows -> S partial, text rows -> Tx partial (+bias only when kbase==0).
__global__ __launch_bounds__(256, 2) void gemm_joint(
    const float* __restrict__ speech, const float* __restrict__ text,
    const float* __restrict__ W, const float* __restrict__ bias,
    float* __restrict__ S, float* __restrict__ Tx, int ktiles)
{
    __shared__ float Xt[TK][XSTR];   // Xt[k][m]
    __shared__ float Wt[TK][WSTR];   // Wt[k][n]

    const int tid = threadIdx.x;
    const int m0 = blockIdx.x * TM;
    const int n0 = blockIdx.y * TN;
    const int z  = blockIdx.z;
    const int kbase = z * ktiles * TK;
    const int tx = tid & 15;         // n: 16 groups of 4 cols
    const int ty = tid >> 4;         // m: 16 groups of 8 rows

    S  += (size_t)z * PSTRIDE;
    Tx += (size_t)z * PSTRIDE;

    const float* xbase = (m0 < MS) ? (speech + (size_t)m0 * D_)
                                   : (text + (size_t)(m0 - MS) * D_);

    float acc[8][4] = {};
    float4 xr[4], wr[2];

    // ---- prologue: load + transpose-store K-tile 0 of this z-half ----
    #pragma unroll
    for (int i = 0; i < 4; ++i) {
        const int q = tid + 256 * i;                  // 0..1023 float4s of X tile
        xr[i] = *(const float4*)(xbase + (size_t)(q >> 3) * D_ + kbase + ((q & 7) << 2));
    }
    #pragma unroll
    for (int i = 0; i < 2; ++i) {
        const int q = tid + 256 * i;                  // 0..511 float4s of W tile
        wr[i] = *(const float4*)(W + (size_t)(n0 + (q >> 3)) * D_ + kbase + ((q & 7) << 2));
    }
    #pragma unroll
    for (int i = 0; i < 4; ++i) {
        const int q = tid + 256 * i;
        const int r = q >> 3, c = (q & 7) << 2;
        Xt[c + 0][r] = xr[i].x; Xt[c + 1][r] = xr[i].y;
        Xt[c + 2][r] = xr[i].z; Xt[c + 3][r] = xr[i].w;
    }
    #pragma unroll
    for (int i = 0; i < 2; ++i) {
        const int q = tid + 256 * i;
        const int r = q >> 3, c = (q & 7) << 2;
        Wt[c + 0][r] = wr[i].x; Wt[c + 1][r] = wr[i].y;
        Wt[c + 2][r] = wr[i].z; Wt[c + 3][r] = wr[i].w;
    }
    __syncthreads();

    for (int t = 0; t < ktiles; ++t) {
        // register-prefetch the next K-tile across the compute phase
        if (t + 1 < ktiles) {
            const int kn = kbase + (t + 1) * TK;
            #pragma unroll
            for (int i = 0; i < 4; ++i) {
                const int q = tid + 256 * i;
                xr[i] = *(const float4*)(xbase + (size_t)(q >> 3) * D_ + kn + ((q & 7) << 2));
            }
            #pragma unroll
            for (int i = 0; i < 2; ++i) {
                const int q = tid + 256 * i;
                wr[i] = *(const float4*)(W + (size_t)(n0 + (q >> 3)) * D_ + kn + ((q & 7) << 2));
            }
        }

        // outer-product compute over the 32 k of this tile
        #pragma unroll 8
        for (int k = 0; k < TK; ++k) {
            const float4 a0 = *(const float4*)&Xt[k][ty * 8];
            const float4 a1 = *(const float4*)&Xt[k][ty * 8 + 4];
            const float4 b0 = *(const float4*)&Wt[k][tx * 4];
            const float av[8] = {a0.x, a0.y, a0.z, a0.w, a1.x, a1.y, a1.z, a1.w};
            const float bv[4] = {b0.x, b0.y, b0.z, b0.w};
            #pragma unroll
            for (int i = 0; i < 8; ++i)
                #pragma unroll
                for (int j = 0; j < 4; ++j)
                    acc[i][j] += av[i] * bv[j];
        }

        if (t + 1 < ktiles) {
            __syncthreads();   // all reads of old tile done
            #pragma unroll
            for (int i = 0; i < 4; ++i) {
                const int q = tid + 256 * i;
                const int r = q >> 3, c = (q & 7) << 2;
                Xt[c + 0][r] = xr[i].x; Xt[c + 1][r] = xr[i].y;
                Xt[c + 2][r] = xr[i].z; Xt[c + 3][r] = xr[i].w;
            }
            #pragma unroll
            for (int i = 0; i < 2; ++i) {
                const int q = tid + 256 * i;
                const int r = q >> 3, c = (q & 7) << 2;
                Wt[c + 0][r] = wr[i].x; Wt[c + 1][r] = wr[i].y;
                Wt[c + 2][r] = wr[i].z; Wt[c + 3][r] = wr[i].w;
            }
            __syncthreads();   // new tile visible
        }
    }

    // ---- epilogue: float4 stores; fold bias into text rows of the z=0 partial ----
    const int vbase = n0 + tx * 4;
    #pragma unroll
    for (int i = 0; i < 8; ++i) {
        const int m = m0 + ty * 8 + i;
        float4 o;
        o.x = acc[i][0]; o.y = acc[i][1]; o.z = acc[i][2]; o.w = acc[i][3];
        if (m < MS) {
            *(float4*)(S + (size_t)m * V_ + vbase) = o;
        } else {
            if (kbase == 0) {
                o.x += bias[vbase + 0];
                o.y += bias[vbase + 1];
                o.z += bias[vbase + 2];
                o.w += bias[vbase + 3];
            }
            *(float4*)(Tx + (size_t)(m - MS) * V_ + vbase) = o;
        }
    }
}

// Kernel 2: out[b,t,u,v] = S[b*T+t, v] + Tx[b*U+u, v]   (bias already in Tx)
// LDS-staged, fill-like store loop. Block = (b, t, u-quarter):
//   stage: summed Tx quarter (32x512 = 64KB) + summed S row (2KB) into LDS,
//   then a PURE ds_read_b128 + v_add + NT-store sweep over a contiguous 64KB
//   output region -- no global loads interleaved with the store stream (the
//   fill kernel proves pure-store loops at ~3 waves/CU reach 6.25 TB/s; every
//   prior bcast variant mixed vmcnt-dependent loads into the stream).
// Sequential bid -> sequential 64KB regions: exactly R3's write order, finer
// grain. Sum order (sv0+sv1)+(tv0+tv1) identical to R3 -> bit-identical out.
// LDS 66KB -> 2 blocks/CU (8 waves). Lens folded into block 0.
template <bool SPLIT>
__global__ __launch_bounds__(256, 2) void bcast_add(
    const float* __restrict__ S, const float* __restrict__ Tx,
    const int* __restrict__ sl, const int* __restrict__ tl,
    float* __restrict__ out)
{
    __shared__ float txs[UCHK * V_];   // summed Tx quarter (64 KB)
    __shared__ float svs[V_];          // summed S row (2 KB)

    const int tid = threadIdx.x;
    const int bid = blockIdx.x;        // 0..8191
    const int uq  = bid & (UQ - 1);
    const int t   = (bid >> 2) & (T_ - 1);
    const int b   = bid >> 11;
    const int bt  = (b << 9) | t;

    if (bid == 0 && tid < 2 * B_) {
        out[LOGITS_ELEMS + tid] = (tid < B_) ? (float)sl[tid]
                                             : (float)tl[tid - B_];
    }

    // ---- stage: summed Tx quarter -> LDS ----
    const f32x4* T4 = (const f32x4*)Tx + ((size_t)b * U_ + uq * UCHK) * V4_;
    f32x4* txs4 = (f32x4*)txs;
    #pragma unroll
    for (int j = 0; j < (UCHK * V4_) / 256; ++j) {    // 16 iters
        const int idx = tid + 256 * j;
        f32x4 v = T4[idx];
        if (SPLIT) v += T4[PS4 + idx];
        txs4[idx] = v;
    }
    // ---- stage: summed S row -> LDS ----
    const f32x4* S4 = (const f32x4*)S + (size_t)bt * V4_;
    if (tid < V4_) {
        f32x4 v = S4[tid];
        if (SPLIT) v += S4[PS4 + tid];
        ((f32x4*)svs)[tid] = v;
    }
    __syncthreads();

    // ---- pure store sweep: contiguous 64KB region ----
    f32x4* O4 = (f32x4*)out + ((size_t)bt * U_ + uq * UCHK) * V4_;
    const f32x4 sv = ((const f32x4*)svs)[tid & (V4_ - 1)];   // loop-invariant
    #pragma unroll
    for (int j = 0; j < (UCHK * V4_) / 256; ++j) {    // 16 iters
        const int idx = tid + 256 * j;
        __builtin_nontemporal_store(txs4[idx] + sv, &O4[idx]);
    }
}

extern "C" void kernel_launch(void* const* d_in, const int* in_sizes, int n_in,
                              void* d_out, int out_size, void* d_ws, size_t ws_size,
                              hipStream_t stream) {
    const float* speech = (const float*)d_in[0];
    const float* text   = (const float*)d_in[1];
    const float* W      = (const float*)d_in[2];
    const float* bias   = (const float*)d_in[3];
    const int*   sl     = (const int*)d_in[4];
    const int*   tl     = (const int*)d_in[5];
    float* out = (float*)d_out;

    float* S  = (float*)d_ws;                 // partial 0: [S | Tx]
    float* Tx = S + S_ELEMS;                  // partial 1 lives at +PSTRIDE

    const bool split = ws_size >= 2 * PSTRIDE * sizeof(float);
    const int nblk2 = B_ * T_ * UQ;           // 8192 blocks

    if (split) {
        dim3 g1(MTOT / TM, V_ / TN, 2);       // 20 x 8 x 2 = 320 blocks
        gemm_joint<<<g1, 256, 0, stream>>>(speech, text, W, bias, S, Tx, (D_ / TK) / 2);
        bcast_add<true><<<nblk2, 256, 0, stream>>>(S, Tx, sl, tl, out);
    } else {
        dim3 g1(MTOT / TM, V_ / TN, 1);       // fallback: unsplit
        gemm_joint<<<g1, 256, 0, stream>>>(speech, text, W, bias, S, Tx, D_ / TK);
        bcast_add<false><<<nblk2, 256, 0, stream>>>(S, Tx, sl, tl, out);
    }
}